// Round 9
// baseline (362.466 us; speedup 1.0000x reference)
//
#include <hip/hip_runtime.h>
#include <hip/hip_fp16.h>
#include <math.h>

#define NN 50000
#define EE 800000
#define TOT_EDGES (EE + NN)   // with self loops
#define FD 3
#define C 64
#define FC 512
#define NODES_PER_GRAPH 5000
#define NUM_GRAPHS 10
#define POOL_CHUNKS 40        // 5000 / 125
#define POOL_NODES_PER_CHUNK 125
#define NEG_SLOPE 0.2f

#define SCAN_BLK 1024
#define SCAN_GRID ((NN + SCAN_BLK - 1) / SCAN_BLK)   // 49

#define HC_BLOCKS 1024        // 4096 waves, ~12 nodes/wave
#define AGG_BLOCKS 1024       // fused aggregate grid (grid-stride over nodes)

// XCD-range-partitioned CSR build (see R5): keeps each XCD's scatter footprint
// L2-resident so line writes coalesce in L2 instead of 64B-per-edge HBM writebacks.
#define NPART 8
#define PART_NODES ((NN + NPART - 1) / NPART)        // 6250
#define CSR_EPT 8
#define CSR_CHUNK (256 * CSR_EPT)                    // 2048 edges / block
#define CSR_CHUNKS ((TOT_EDGES + CSR_CHUNK - 1) / CSR_CHUNK)

// ---------------- CSR build ----------------

__global__ void k_init_counts(int* counts) {
    int i = blockIdx.x * blockDim.x + threadIdx.x;
    if (i < NN) counts[i] = 0;   // self loops folded into partitioned count
}

__global__ void k_count_part(const int* __restrict__ dst, int* __restrict__ counts) {
    int part = blockIdx.x & (NPART - 1);
    int chunk = blockIdx.x >> 3;
    int lo = part * PART_NODES, hi = lo + PART_NODES;
    int base = chunk * CSR_CHUNK + threadIdx.x;
#pragma unroll
    for (int e = 0; e < CSR_EPT; ++e) {
        int i = base + e * 256;
        if (i < TOT_EDGES) {
            int d = (i < EE) ? dst[i] : (i - EE);
            if (d >= lo && d < hi) atomicAdd(&counts[d], 1);
        }
    }
}

// stage 1: per-block LDS scan (exclusive within block) + block sums
__global__ void k_scan1(const int* __restrict__ counts, int* __restrict__ offsets,
                        int* __restrict__ blocksums) {
    int tid = threadIdx.x, blk = blockIdx.x;
    int i = blk * SCAN_BLK + tid;
    int v = (i < NN) ? counts[i] : 0;
    __shared__ int buf[SCAN_BLK];
    buf[tid] = v;
    __syncthreads();
    for (int off = 1; off < SCAN_BLK; off <<= 1) {
        int t = (tid >= off) ? buf[tid - off] : 0;
        __syncthreads();
        buf[tid] += t;
        __syncthreads();
    }
    if (i < NN) offsets[i] = buf[tid] - v;   // exclusive
    if (tid == SCAN_BLK - 1) blocksums[blk] = buf[tid];
}

// stage 2: serial scan of 49 block sums (one lane) -> in-place exclusive bases + total
__global__ void k_scan2(int* __restrict__ blocksums, int* __restrict__ offsets) {
    if (threadIdx.x == 0) {
        int run = 0;
        for (int b = 0; b < SCAN_GRID; ++b) {
            int v = blocksums[b];
            blocksums[b] = run;
            run += v;
        }
        offsets[NN] = run;   // = TOT_EDGES
    }
}

// stage 3: add block base, emit cursors
__global__ void k_scan3(int* __restrict__ offsets, int* __restrict__ cursors,
                        const int* __restrict__ blocksums) {
    int tid = threadIdx.x, blk = blockIdx.x;
    int i = blk * SCAN_BLK + tid;
    if (i < NN) {
        int o = offsets[i] + blocksums[blk];
        offsets[i] = o;
        cursors[i] = o;
    }
}

__global__ void k_scatter_part(const int* __restrict__ src, const int* __restrict__ dst,
                               int* __restrict__ cursors, int* __restrict__ ssrc) {
    int part = blockIdx.x & (NPART - 1);
    int chunk = blockIdx.x >> 3;
    int lo = part * PART_NODES, hi = lo + PART_NODES;
    int base = chunk * CSR_CHUNK + threadIdx.x;
#pragma unroll
    for (int e = 0; e < CSR_EPT; ++e) {
        int i = base + e * 256;
        if (i < TOT_EDGES) {
            int d = (i < EE) ? dst[i] : (i - EE);
            if (d >= lo && d < hi) {
                int s = (i < EE) ? src[i] : d;
                int idx = atomicAdd(&cursors[d], 1);
                ssrc[idx] = s;
            }
        }
    }
}

// ---------------- GAT layer kernels ----------------

// Layer-1 projection only: h = x @ W1 (FD->C); es/ed. Wave-per-node grid-stride,
// W column in VGPRs, wave-uniform x-row pointer. h stored fp16.
template<int IN_DIM>
__global__ void k_hcompute_t(const float* __restrict__ x,
                             const float* __restrict__ W,
                             const float* __restrict__ a_s, const float* __restrict__ a_d,
                             __half* __restrict__ h, float* __restrict__ es,
                             float* __restrict__ ed, int nwaves_total) {
    int lane = threadIdx.x & 63;
    int wid = (blockIdx.x * blockDim.x + threadIdx.x) >> 6;

    float wcol[IN_DIM];
#pragma unroll
    for (int k = 0; k < IN_DIM; ++k) wcol[k] = W[k * 64 + lane];
    float asl = a_s[lane], adl = a_d[lane];

    for (int n = wid; n < NN; n += nwaves_total) {
        int nu = __builtin_amdgcn_readfirstlane(n);
        const float* xrow = x + (size_t)nu * IN_DIM;
        float acc = 0.f;
#pragma unroll
        for (int k = 0; k < IN_DIM; ++k) acc = fmaf(xrow[k], wcol[k], acc);
        h[(size_t)nu * 64 + lane] = __float2half(acc);
        float vs = acc * asl;
        float vd = acc * adl;
        for (int w = 32; w >= 1; w >>= 1) {
            vs += __shfl_xor(vs, w);
            vd += __shfl_xor(vd, w);
        }
        if (lane == 0) { es[nu] = vs; ed[nu] = vd; }
    }
}

// Fused GAT aggregate (+ next-layer projection).
// One wave per dst node (grid-stride). Single-pass softmax without max-subtraction
// (|e| <~ 1 with 0.1-scaled weights; exp(e)/sum == exp(e-m)/sum exactly).
// Gather: 8 edges/iter, grp=lane>>3 picks edge, c=lane&7 picks 8 fp16 channels
// (one 16B load/lane). After the butterfly reduce EVERY lane holds the full
// output row (8x redundant), so for HAS_NEXT the epilogue computes
// h_next = relu(v) @ Wn entirely in-wave: wn[k]=Wn[k][lane] lives in VGPRs
// (amortized over ~12 nodes/wave), row broadcast via 64 unrolled shfls.
// Eliminates the separate hcompute dispatch and the fp32 intermediate buffer.
template<int HAS_NEXT>
__global__ void k_agg_fused(const __half* __restrict__ h,
                            const float* __restrict__ es, const float* __restrict__ ed,
                            const int* __restrict__ offsets, const int* __restrict__ ssrc,
                            const float* __restrict__ bias,
                            const float* __restrict__ Wn,
                            const float* __restrict__ asn, const float* __restrict__ adn,
                            __half* __restrict__ hn, float* __restrict__ esn,
                            float* __restrict__ edn_out,
                            float* __restrict__ out_final,
                            int nwaves_total) {
    int lane = threadIdx.x & 63;
    int wid = (blockIdx.x * blockDim.x + threadIdx.x) >> 6;
    int grp = lane >> 3;        // 0..7 : which edge of the group
    int c   = lane & 7;         // channel block: halves [8c, 8c+8)

    float wn[HAS_NEXT ? 64 : 1];
    float asl = 0.f, adl = 0.f;
    if (HAS_NEXT) {
#pragma unroll
        for (int k = 0; k < 64; ++k) wn[k] = Wn[k * 64 + lane];
        asl = asn[lane];
        adl = adn[lane];
    }
    float4 blo = *(const float4*)&bias[c * 8];
    float4 bhi = *(const float4*)&bias[c * 8 + 4];
    float bb[8] = {blo.x, blo.y, blo.z, blo.w, bhi.x, bhi.y, bhi.z, bhi.w};

    for (int n = wid; n < NN; n += nwaves_total) {
        int beg = offsets[n], end = offsets[n + 1];
        float ednv = ed[n];
        float s = 0.f;
        float acc[8];
#pragma unroll
        for (int i = 0; i < 8; ++i) acc[i] = 0.f;

        for (int j0 = beg; j0 < end; j0 += 8) {
            int jg = j0 + grp;
            if (jg < end) {
                int sj = ssrc[jg];
                float e = es[sj] + ednv;
                e = (e > 0.f) ? e : NEG_SLOPE * e;
                float p = __expf(e);
                s += p;
                float4 raw = *(const float4*)&h[(size_t)sj * 64 + c * 8];
                const __half2* hp = (const __half2*)&raw;
#pragma unroll
                for (int q = 0; q < 4; ++q) {
                    float2 f = __half22float2(hp[q]);
                    acc[2 * q]     = fmaf(p, f.x, acc[2 * q]);
                    acc[2 * q + 1] = fmaf(p, f.y, acc[2 * q + 1]);
                }
            }
        }
        // reduce s and acc across the 8 edge-groups -> all lanes get full sums
#pragma unroll
        for (int w = 8; w <= 32; w <<= 1) {
            s += __shfl_xor(s, w);
#pragma unroll
            for (int i = 0; i < 8; ++i) acc[i] += __shfl_xor(acc[i], w);
        }
        float inv_s = 1.0f / s;
        float v[8];
#pragma unroll
        for (int i = 0; i < 8; ++i) {
            v[i] = acc[i] * inv_s + bb[i];
            if (HAS_NEXT) v[i] = fmaxf(v[i], 0.f);   // relu on layers 1..3
        }

        if (HAS_NEXT) {
            // h_next[lane] = sum_k row[k] * Wn[k][lane]; row[k] lives as
            // v[k&7] on lane (k>>3) (and its 7 replicas).
            float hv = 0.f;
#pragma unroll
            for (int k = 0; k < 64; ++k) {
                float rowk = __shfl(v[k & 7], k >> 3);
                hv = fmaf(rowk, wn[k], hv);
            }
            hn[(size_t)n * 64 + lane] = __float2half(hv);
            float vs = hv * asl;
            float vd = hv * adl;
            for (int w = 32; w >= 1; w >>= 1) {
                vs += __shfl_xor(vs, w);
                vd += __shfl_xor(vd, w);
            }
            if (lane == 0) { esn[n] = vs; edn_out[n] = vd; }
        } else {
            if (grp == 0) {
                *(float4*)&out_final[(size_t)n * 64 + c * 8]     = make_float4(v[0], v[1], v[2], v[3]);
                *(float4*)&out_final[(size_t)n * 64 + c * 8 + 4] = make_float4(v[4], v[5], v[6], v[7]);
            }
        }
    }
}

// ---------------- epilogue ----------------

// stage 1: 400 blocks = 10 graphs x 40 chunks of 125 nodes. Deterministic.
__global__ void k_pool1(const float* __restrict__ h, float* __restrict__ partial) {
    int blk = blockIdx.x;
    int g = blk / POOL_CHUNKS, c = blk % POOL_CHUNKS;
    int wave = threadIdx.x >> 6, lane = threadIdx.x & 63;
    int base = g * NODES_PER_GRAPH + c * POOL_NODES_PER_CHUNK;
    float acc = 0.f;
    for (int i = wave; i < POOL_NODES_PER_CHUNK; i += 4)
        acc += h[(size_t)(base + i) * 64 + lane];
    __shared__ float buf[4][64];
    buf[wave][lane] = acc;
    __syncthreads();
    if (wave == 0)
        partial[blk * 64 + lane] = buf[0][lane] + buf[1][lane] + buf[2][lane] + buf[3][lane];
}

// stage 2: 10 blocks x 64 threads, reduce 40 partials each.
__global__ void k_pool2(const float* __restrict__ partial, float* __restrict__ pooled) {
    int g = blockIdx.x;
    int lane = threadIdx.x;  // 64
    float acc = 0.f;
    for (int c = 0; c < POOL_CHUNKS; ++c)
        acc += partial[(g * POOL_CHUNKS + c) * 64 + lane];
    pooled[g * 64 + lane] = acc * (1.0f / NODES_PER_GRAPH);
}

__global__ void k_value(const float* __restrict__ pooled,
                        const float* __restrict__ Wv1, const float* __restrict__ bv1,
                        const float* __restrict__ Wv2, const float* __restrict__ bv2,
                        float* __restrict__ value) {
    int g = blockIdx.x;
    int j = threadIdx.x;   // 512
    __shared__ float pl[64];
    if (j < 64) pl[j] = pooled[g * 64 + j];
    __syncthreads();
    float acc = bv1[j];
    for (int c = 0; c < 64; ++c) acc += pl[c] * Wv1[c * 512 + j];
    acc = fmaxf(acc, 0.f);
    float t = acc * Wv2[j];
    for (int w = 32; w >= 1; w >>= 1) t += __shfl_xor(t, w);
    __shared__ float red[8];
    int wave = j >> 6, lane = j & 63;
    if (lane == 0) red[wave] = t;
    __syncthreads();
    if (j == 0) {
        float v = 0.f;
        for (int w = 0; w < 8; ++w) v += red[w];
        value[g] = v + bv2[0];
    }
}

// ---------------- launcher ----------------

extern "C" void kernel_launch(void* const* d_in, const int* in_sizes, int n_in,
                              void* d_out, int out_size, void* d_ws, size_t ws_size,
                              hipStream_t stream) {
    const float* x   = (const float*)d_in[0];
    const int*   ei  = (const int*)d_in[1];     // (2, E): row0=src, row1=dst
    const float* W1  = (const float*)d_in[2];
    const float* as1 = (const float*)d_in[3];
    const float* ad1 = (const float*)d_in[4];
    const float* b1  = (const float*)d_in[5];
    const float* Wh  = (const float*)d_in[6];   // (2,64,64)
    const float* ash = (const float*)d_in[7];
    const float* adh = (const float*)d_in[8];
    const float* bh  = (const float*)d_in[9];
    const float* W2  = (const float*)d_in[10];
    const float* as2 = (const float*)d_in[11];
    const float* ad2 = (const float*)d_in[12];
    const float* b2  = (const float*)d_in[13];
    const float* Wv1 = (const float*)d_in[14];
    const float* bv1 = (const float*)d_in[15];
    const float* Wv2 = (const float*)d_in[16];
    const float* bv2 = (const float*)d_in[17];

    const int* e_src = ei;
    const int* e_dst = ei + EE;

    // workspace carve-up (256B aligned)
    char* p = (char*)d_ws;
    auto carve = [&](size_t bytes) {
        char* r = p;
        p += (bytes + 255) & ~(size_t)255;
        return r;
    };
    int*    counts    = (int*)carve(NN * 4);
    int*    offsets   = (int*)carve((NN + 1) * 4);
    int*    cursors   = (int*)carve(NN * 4);
    int*    ssrc      = (int*)carve(TOT_EDGES * 4);
    int*    blocksums = (int*)carve(SCAN_GRID * 4);
    __half* bufHA     = (__half*)carve((size_t)NN * 64 * 2);  // fp16 gather tables
    __half* bufHB     = (__half*)carve((size_t)NN * 64 * 2);  // (ping-pong)
    float*  esA       = (float*)carve(NN * 4);
    float*  edA       = (float*)carve(NN * 4);
    float*  esB       = (float*)carve(NN * 4);
    float*  edB       = (float*)carve(NN * 4);
    float*  partial   = (float*)carve((size_t)NUM_GRAPHS * POOL_CHUNKS * 64 * 4);

    float* out_h      = (float*)d_out;                 // [N, 64]
    float* out_pooled = out_h + (size_t)NN * 64;       // [10, 64]
    float* out_value  = out_pooled + NUM_GRAPHS * 64;  // [10]

    // CSR build (reused by all 4 layers)
    k_init_counts<<<(NN + 255) / 256, 256, 0, stream>>>(counts);
    k_count_part<<<NPART * CSR_CHUNKS, 256, 0, stream>>>(e_dst, counts);
    k_scan1<<<SCAN_GRID, SCAN_BLK, 0, stream>>>(counts, offsets, blocksums);
    k_scan2<<<1, 64, 0, stream>>>(blocksums, offsets);
    k_scan3<<<SCAN_GRID, SCAN_BLK, 0, stream>>>(offsets, cursors, blocksums);
    k_scatter_part<<<NPART * CSR_CHUNKS, 256, 0, stream>>>(e_src, e_dst, cursors, ssrc);

    const int HC_WAVES  = HC_BLOCKS * 256 / 64;   // 4096
    const int AGG_WAVES = AGG_BLOCKS * 256 / 64;  // 4096

    // layer 1 projection: x @ W1 -> (HA, esA, edA)
    k_hcompute_t<FD><<<HC_BLOCKS, 256, 0, stream>>>(x, W1, as1, ad1, bufHA, esA, edA, HC_WAVES);

    // GAT1 aggregate + project into layer-2 table: (HA) -> (HB, esB, edB)
    k_agg_fused<1><<<AGG_BLOCKS, 256, 0, stream>>>(bufHA, esA, edA, offsets, ssrc, b1,
                                                   Wh + 0 * 64 * 64, ash + 0 * 64, adh + 0 * 64,
                                                   bufHB, esB, edB, nullptr, AGG_WAVES);
    // GAT2 aggregate + project into layer-3 table: (HB) -> (HA, esA, edA)
    k_agg_fused<1><<<AGG_BLOCKS, 256, 0, stream>>>(bufHB, esB, edB, offsets, ssrc, bh + 0 * 64,
                                                   Wh + 1 * 64 * 64, ash + 1 * 64, adh + 1 * 64,
                                                   bufHA, esA, edA, nullptr, AGG_WAVES);
    // GAT3 aggregate + project into layer-4 table: (HA) -> (HB, esB, edB)
    k_agg_fused<1><<<AGG_BLOCKS, 256, 0, stream>>>(bufHA, esA, edA, offsets, ssrc, bh + 1 * 64,
                                                   W2, as2, ad2,
                                                   bufHB, esB, edB, nullptr, AGG_WAVES);
    // GAT4 aggregate -> final fp32 output (no relu, no projection)
    k_agg_fused<0><<<AGG_BLOCKS, 256, 0, stream>>>(bufHB, esB, edB, offsets, ssrc, b2,
                                                   nullptr, nullptr, nullptr,
                                                   nullptr, nullptr, nullptr, out_h, AGG_WAVES);

    // pooling + value head
    k_pool1<<<NUM_GRAPHS * POOL_CHUNKS, 256, 0, stream>>>(out_h, partial);
    k_pool2<<<NUM_GRAPHS, 64, 0, stream>>>(partial, out_pooled);
    k_value<<<NUM_GRAPHS, 512, 0, stream>>>(out_pooled, Wv1, bv1, Wv2, bv2, out_value);
}

// Round 10
// 283.639 us; speedup vs baseline: 1.2779x; 1.2779x over previous
//
#include <hip/hip_runtime.h>
#include <hip/hip_fp16.h>
#include <math.h>

#define NN 50000
#define EE 800000
#define TOT_EDGES (EE + NN)   // with self loops
#define FD 3
#define C 64
#define FC 512
#define NODES_PER_GRAPH 5000
#define NUM_GRAPHS 10
#define POOL_CHUNKS 40        // 5000 / 125
#define POOL_NODES_PER_CHUNK 125
#define NEG_SLOPE 0.2f

#define SCAN_BLK 1024
#define SCAN_GRID ((NN + SCAN_BLK - 1) / SCAN_BLK)   // 49

#define HC_BLOCKS 1024        // 4096 waves, ~12 nodes/wave

// XCD-range-partitioned CSR build (see R5): keeps each XCD's scatter footprint
// L2-resident so line writes coalesce in L2 instead of 64B-per-edge HBM writebacks.
#define NPART 8
#define PART_NODES ((NN + NPART - 1) / NPART)        // 6250
#define CSR_EPT 8
#define CSR_CHUNK (256 * CSR_EPT)                    // 2048 edges / block
#define CSR_CHUNKS ((TOT_EDGES + CSR_CHUNK - 1) / CSR_CHUNK)

// ---------------- CSR build ----------------

__global__ void k_init_counts(int* counts) {
    int i = blockIdx.x * blockDim.x + threadIdx.x;
    if (i < NN) counts[i] = 0;   // self loops folded into partitioned count
}

__global__ void k_count_part(const int* __restrict__ dst, int* __restrict__ counts) {
    int part = blockIdx.x & (NPART - 1);
    int chunk = blockIdx.x >> 3;
    int lo = part * PART_NODES, hi = lo + PART_NODES;
    int base = chunk * CSR_CHUNK + threadIdx.x;
#pragma unroll
    for (int e = 0; e < CSR_EPT; ++e) {
        int i = base + e * 256;
        if (i < TOT_EDGES) {
            int d = (i < EE) ? dst[i] : (i - EE);
            if (d >= lo && d < hi) atomicAdd(&counts[d], 1);
        }
    }
}

// stage 1: per-block LDS scan (exclusive within block) + block sums
__global__ void k_scan1(const int* __restrict__ counts, int* __restrict__ offsets,
                        int* __restrict__ blocksums) {
    int tid = threadIdx.x, blk = blockIdx.x;
    int i = blk * SCAN_BLK + tid;
    int v = (i < NN) ? counts[i] : 0;
    __shared__ int buf[SCAN_BLK];
    buf[tid] = v;
    __syncthreads();
    for (int off = 1; off < SCAN_BLK; off <<= 1) {
        int t = (tid >= off) ? buf[tid - off] : 0;
        __syncthreads();
        buf[tid] += t;
        __syncthreads();
    }
    if (i < NN) offsets[i] = buf[tid] - v;   // exclusive
    if (tid == SCAN_BLK - 1) blocksums[blk] = buf[tid];
}

// stage 2: serial scan of 49 block sums (one lane) -> in-place exclusive bases + total
__global__ void k_scan2(int* __restrict__ blocksums, int* __restrict__ offsets) {
    if (threadIdx.x == 0) {
        int run = 0;
        for (int b = 0; b < SCAN_GRID; ++b) {
            int v = blocksums[b];
            blocksums[b] = run;
            run += v;
        }
        offsets[NN] = run;   // = TOT_EDGES
    }
}

// stage 3: add block base, emit cursors
__global__ void k_scan3(int* __restrict__ offsets, int* __restrict__ cursors,
                        const int* __restrict__ blocksums) {
    int tid = threadIdx.x, blk = blockIdx.x;
    int i = blk * SCAN_BLK + tid;
    if (i < NN) {
        int o = offsets[i] + blocksums[blk];
        offsets[i] = o;
        cursors[i] = o;
    }
}

__global__ void k_scatter_part(const int* __restrict__ src, const int* __restrict__ dst,
                               int* __restrict__ cursors, int* __restrict__ ssrc) {
    int part = blockIdx.x & (NPART - 1);
    int chunk = blockIdx.x >> 3;
    int lo = part * PART_NODES, hi = lo + PART_NODES;
    int base = chunk * CSR_CHUNK + threadIdx.x;
#pragma unroll
    for (int e = 0; e < CSR_EPT; ++e) {
        int i = base + e * 256;
        if (i < TOT_EDGES) {
            int d = (i < EE) ? dst[i] : (i - EE);
            if (d >= lo && d < hi) {
                int s = (i < EE) ? src[i] : d;
                int idx = atomicAdd(&cursors[d], 1);
                ssrc[idx] = s;
            }
        }
    }
}

// ---------------- GAT layer kernels ----------------

// Layer-1 projection: h = x @ W1 (FD=3 -> C); es/ed. Wave-per-node grid-stride,
// W column in VGPRs, wave-uniform x-row pointer. h stored fp16.
__global__ void k_hcompute_f3(const float* __restrict__ x,
                              const float* __restrict__ W,
                              const float* __restrict__ a_s, const float* __restrict__ a_d,
                              __half* __restrict__ h, float* __restrict__ es,
                              float* __restrict__ ed, int nwaves_total) {
    int lane = threadIdx.x & 63;
    int wid = (blockIdx.x * blockDim.x + threadIdx.x) >> 6;

    float wcol[FD];
#pragma unroll
    for (int k = 0; k < FD; ++k) wcol[k] = W[k * 64 + lane];
    float asl = a_s[lane], adl = a_d[lane];

    for (int n = wid; n < NN; n += nwaves_total) {
        int nu = __builtin_amdgcn_readfirstlane(n);
        const float* xrow = x + (size_t)nu * FD;
        float acc = 0.f;
#pragma unroll
        for (int k = 0; k < FD; ++k) acc = fmaf(xrow[k], wcol[k], acc);
        h[(size_t)nu * 64 + lane] = __float2half(acc);
        float vs = acc * asl;
        float vd = acc * adl;
        for (int w = 32; w >= 1; w >>= 1) {
            vs += __shfl_xor(vs, w);
            vd += __shfl_xor(vd, w);
        }
        if (lane == 0) { es[nu] = vs; ed[nu] = vd; }
    }
}

// Hidden/final projection: h = x16 @ W (C -> C); x16 is the fp16 layer-boundary
// buffer. Row read as 32 wave-uniform __half2 loads (scalarizable).
__global__ void k_hcompute_h64(const __half* __restrict__ x,
                               const float* __restrict__ W,
                               const float* __restrict__ a_s, const float* __restrict__ a_d,
                               __half* __restrict__ h, float* __restrict__ es,
                               float* __restrict__ ed, int nwaves_total) {
    int lane = threadIdx.x & 63;
    int wid = (blockIdx.x * blockDim.x + threadIdx.x) >> 6;

    float wcol[64];
#pragma unroll
    for (int k = 0; k < 64; ++k) wcol[k] = W[k * 64 + lane];
    float asl = a_s[lane], adl = a_d[lane];

    for (int n = wid; n < NN; n += nwaves_total) {
        int nu = __builtin_amdgcn_readfirstlane(n);
        const __half2* xr = (const __half2*)(x + (size_t)nu * 64);
        float acc = 0.f;
#pragma unroll
        for (int q = 0; q < 32; ++q) {
            float2 f = __half22float2(xr[q]);
            acc = fmaf(f.x, wcol[2 * q], acc);
            acc = fmaf(f.y, wcol[2 * q + 1], acc);
        }
        h[(size_t)nu * 64 + lane] = __float2half(acc);
        float vs = acc * asl;
        float vd = acc * adl;
        for (int w = 32; w >= 1; w >>= 1) {
            vs += __shfl_xor(vs, w);
            vd += __shfl_xor(vd, w);
        }
        if (lane == 0) { es[nu] = vs; ed[nu] = vd; }
    }
}

// One wave per dst node, SINGLE fused pass (R7/R8 structure). Softmax without
// max-subtraction: with 0.1-scaled weights |e| <~ 1, exp never overflows, and
// exp(e)/sum(exp(e)) == exp(e-m)/sum(exp(e-m)) exactly in real arithmetic.
// 8 edges/iter: grp=lane>>3 picks the edge, c=lane&7 picks 8 fp16 channels
// (one 16B load/lane, 8 random 128B rows in flight per load instr).
// HIDDEN=1: relu + fp16 16B store to the layer boundary buffer.
// HIDDEN=0: final layer, fp32 output, no relu.
template<int HIDDEN>
__global__ void k_aggregate(const __half* __restrict__ h,
                            const float* __restrict__ es, const float* __restrict__ ed,
                            const int* __restrict__ offsets, const int* __restrict__ ssrc,
                            const float* __restrict__ bias,
                            __half* __restrict__ outH, float* __restrict__ outF) {
    int gtid = blockIdx.x * blockDim.x + threadIdx.x;
    int n = gtid >> 6;
    int lane = threadIdx.x & 63;
    if (n >= NN) return;
    int beg = offsets[n], end = offsets[n + 1];
    float ednv = ed[n];

    int grp = lane >> 3;        // 0..7 : which edge of the group
    int c   = lane & 7;         // channel block: halves [8c, 8c+8)
    float s = 0.f;
    float acc[8];
#pragma unroll
    for (int i = 0; i < 8; ++i) acc[i] = 0.f;

    for (int j0 = beg; j0 < end; j0 += 8) {
        int jg = j0 + grp;
        if (jg < end) {
            int sj = ssrc[jg];
            float e = es[sj] + ednv;
            e = (e > 0.f) ? e : NEG_SLOPE * e;
            float p = __expf(e);
            s += p;
            float4 raw = *(const float4*)&h[(size_t)sj * 64 + c * 8];
            const __half2* hp = (const __half2*)&raw;
#pragma unroll
            for (int q = 0; q < 4; ++q) {
                float2 f = __half22float2(hp[q]);
                acc[2 * q]     = fmaf(p, f.x, acc[2 * q]);
                acc[2 * q + 1] = fmaf(p, f.y, acc[2 * q + 1]);
            }
        }
    }
    // reduce s and acc across the 8 edge-groups (lanes c, c+8, ..., c+56)
#pragma unroll
    for (int w = 8; w <= 32; w <<= 1) {
        s += __shfl_xor(s, w);
#pragma unroll
        for (int i = 0; i < 8; ++i) acc[i] += __shfl_xor(acc[i], w);
    }
    if (grp == 0) {
        float inv_s = 1.0f / s;
        float v[8];
#pragma unroll
        for (int i = 0; i < 8; ++i) {
            v[i] = acc[i] * inv_s + bias[c * 8 + i];
            if (HIDDEN) v[i] = fmaxf(v[i], 0.f);
        }
        if (HIDDEN) {
            __half2 hv[4];
#pragma unroll
            for (int q = 0; q < 4; ++q)
                hv[q] = __floats2half2_rn(v[2 * q], v[2 * q + 1]);
            *(float4*)&outH[(size_t)n * 64 + c * 8] = *(float4*)hv;   // 16B
        } else {
            *(float4*)&outF[(size_t)n * 64 + c * 8]     = make_float4(v[0], v[1], v[2], v[3]);
            *(float4*)&outF[(size_t)n * 64 + c * 8 + 4] = make_float4(v[4], v[5], v[6], v[7]);
        }
    }
}

// ---------------- epilogue ----------------

// stage 1: 400 blocks = 10 graphs x 40 chunks of 125 nodes. Deterministic.
__global__ void k_pool1(const float* __restrict__ h, float* __restrict__ partial) {
    int blk = blockIdx.x;
    int g = blk / POOL_CHUNKS, c = blk % POOL_CHUNKS;
    int wave = threadIdx.x >> 6, lane = threadIdx.x & 63;
    int base = g * NODES_PER_GRAPH + c * POOL_NODES_PER_CHUNK;
    float acc = 0.f;
    for (int i = wave; i < POOL_NODES_PER_CHUNK; i += 4)
        acc += h[(size_t)(base + i) * 64 + lane];
    __shared__ float buf[4][64];
    buf[wave][lane] = acc;
    __syncthreads();
    if (wave == 0)
        partial[blk * 64 + lane] = buf[0][lane] + buf[1][lane] + buf[2][lane] + buf[3][lane];
}

// stage 2: 10 blocks x 64 threads, reduce 40 partials each.
__global__ void k_pool2(const float* __restrict__ partial, float* __restrict__ pooled) {
    int g = blockIdx.x;
    int lane = threadIdx.x;  // 64
    float acc = 0.f;
    for (int c = 0; c < POOL_CHUNKS; ++c)
        acc += partial[(g * POOL_CHUNKS + c) * 64 + lane];
    pooled[g * 64 + lane] = acc * (1.0f / NODES_PER_GRAPH);
}

__global__ void k_value(const float* __restrict__ pooled,
                        const float* __restrict__ Wv1, const float* __restrict__ bv1,
                        const float* __restrict__ Wv2, const float* __restrict__ bv2,
                        float* __restrict__ value) {
    int g = blockIdx.x;
    int j = threadIdx.x;   // 512
    __shared__ float pl[64];
    if (j < 64) pl[j] = pooled[g * 64 + j];
    __syncthreads();
    float acc = bv1[j];
    for (int c = 0; c < 64; ++c) acc += pl[c] * Wv1[c * 512 + j];
    acc = fmaxf(acc, 0.f);
    float t = acc * Wv2[j];
    for (int w = 32; w >= 1; w >>= 1) t += __shfl_xor(t, w);
    __shared__ float red[8];
    int wave = j >> 6, lane = j & 63;
    if (lane == 0) red[wave] = t;
    __syncthreads();
    if (j == 0) {
        float v = 0.f;
        for (int w = 0; w < 8; ++w) v += red[w];
        value[g] = v + bv2[0];
    }
}

// ---------------- launcher ----------------

extern "C" void kernel_launch(void* const* d_in, const int* in_sizes, int n_in,
                              void* d_out, int out_size, void* d_ws, size_t ws_size,
                              hipStream_t stream) {
    const float* x   = (const float*)d_in[0];
    const int*   ei  = (const int*)d_in[1];     // (2, E): row0=src, row1=dst
    const float* W1  = (const float*)d_in[2];
    const float* as1 = (const float*)d_in[3];
    const float* ad1 = (const float*)d_in[4];
    const float* b1  = (const float*)d_in[5];
    const float* Wh  = (const float*)d_in[6];   // (2,64,64)
    const float* ash = (const float*)d_in[7];
    const float* adh = (const float*)d_in[8];
    const float* bh  = (const float*)d_in[9];
    const float* W2  = (const float*)d_in[10];
    const float* as2 = (const float*)d_in[11];
    const float* ad2 = (const float*)d_in[12];
    const float* b2  = (const float*)d_in[13];
    const float* Wv1 = (const float*)d_in[14];
    const float* bv1 = (const float*)d_in[15];
    const float* Wv2 = (const float*)d_in[16];
    const float* bv2 = (const float*)d_in[17];

    const int* e_src = ei;
    const int* e_dst = ei + EE;

    // workspace carve-up (256B aligned)
    char* p = (char*)d_ws;
    auto carve = [&](size_t bytes) {
        char* r = p;
        p += (bytes + 255) & ~(size_t)255;
        return r;
    };
    int*    counts    = (int*)carve(NN * 4);
    int*    offsets   = (int*)carve((NN + 1) * 4);
    int*    cursors   = (int*)carve(NN * 4);
    int*    ssrc      = (int*)carve(TOT_EDGES * 4);
    int*    blocksums = (int*)carve(SCAN_GRID * 4);
    __half* bufH      = (__half*)carve((size_t)NN * 64 * 2);   // fp16 gather table
    __half* bufB16    = (__half*)carve((size_t)NN * 64 * 2);   // fp16 layer boundary
    float*  es        = (float*)carve(NN * 4);
    float*  ed        = (float*)carve(NN * 4);
    float*  partial   = (float*)carve((size_t)NUM_GRAPHS * POOL_CHUNKS * 64 * 4);

    float* out_h      = (float*)d_out;                 // [N, 64]
    float* out_pooled = out_h + (size_t)NN * 64;       // [10, 64]
    float* out_value  = out_pooled + NUM_GRAPHS * 64;  // [10]

    // CSR build (reused by all 4 layers)
    k_init_counts<<<(NN + 255) / 256, 256, 0, stream>>>(counts);
    k_count_part<<<NPART * CSR_CHUNKS, 256, 0, stream>>>(e_dst, counts);
    k_scan1<<<SCAN_GRID, SCAN_BLK, 0, stream>>>(counts, offsets, blocksums);
    k_scan2<<<1, 64, 0, stream>>>(blocksums, offsets);
    k_scan3<<<SCAN_GRID, SCAN_BLK, 0, stream>>>(offsets, cursors, blocksums);
    k_scatter_part<<<NPART * CSR_CHUNKS, 256, 0, stream>>>(e_src, e_dst, cursors, ssrc);

    const int HBLK = (NN + 3) / 4;             // aggregate: 4 waves/block, 1 node/wave
    const int HC_WAVES = HC_BLOCKS * 256 / 64; // 4096

    // layer 1: FD -> C, relu; boundary buffer is fp16
    k_hcompute_f3<<<HC_BLOCKS, 256, 0, stream>>>(x, W1, as1, ad1, bufH, es, ed, HC_WAVES);
    k_aggregate<1><<<HBLK, 256, 0, stream>>>(bufH, es, ed, offsets, ssrc, b1, bufB16, nullptr);

    // hidden layers: C -> C, relu
    for (int i = 0; i < 2; ++i) {
        k_hcompute_h64<<<HC_BLOCKS, 256, 0, stream>>>(bufB16, Wh + i * 64 * 64, ash + i * 64,
                                                      adh + i * 64, bufH, es, ed, HC_WAVES);
        k_aggregate<1><<<HBLK, 256, 0, stream>>>(bufH, es, ed, offsets, ssrc, bh + i * 64,
                                                 bufB16, nullptr);
    }

    // layer 4: C -> OUT, no relu, write straight to d_out (fp32)
    k_hcompute_h64<<<HC_BLOCKS, 256, 0, stream>>>(bufB16, W2, as2, ad2, bufH, es, ed, HC_WAVES);
    k_aggregate<0><<<HBLK, 256, 0, stream>>>(bufH, es, ed, offsets, ssrc, b2, nullptr, out_h);

    // pooling + value head
    k_pool1<<<NUM_GRAPHS * POOL_CHUNKS, 256, 0, stream>>>(out_h, partial);
    k_pool2<<<NUM_GRAPHS, 64, 0, stream>>>(partial, out_pooled);
    k_value<<<NUM_GRAPHS, 512, 0, stream>>>(out_pooled, Wv1, bv1, Wv2, bv2, out_value);
}